// Round 8
// baseline (189.239 us; speedup 1.0000x reference)
//
#include <hip/hip_runtime.h>
#include <hip/hip_bf16.h>

// DiagonalEmbedder: out[b,i] = 0.5 * ( x2@inv.T - 2 x@(mean*inv).T + c_i )
// 2-term fp32-split bf16 GEMM (passed r7): A' = [FAh|FAl] (4096x512),
// B = [inv, -2*mean*inv] single-bf16 (8192x256), logical K=512 (B wraps t&3).
// r7 post-mortem: 1 block/CU lockstep 2-phase -> CU idles at vmcnt (staging
// supply 4 TB/s vs 11-13 TB/s achieved by deeper schedules). This round:
// 256x128 tile, THREE LDS buffers (144 KB), tile t's loads get 2 full
// iterations in flight. Everything else (swizzle, counted vmcnt, L2 grouping,
// nt epilogue) carried over.

#define BATCH 4096
#define N_IN  8192
#define DIM   128
#define KPA   512
#define KPB   256
#define PD_THR 1e-6f

#define BM 256
#define BN 128
#define BK 64
#define NT (KPA / BK)       // 8 K-tiles
#define BUFE (BM * BK + BN * BK)   // 24576 shorts per buffer (A 32KB + B 16KB)

typedef __attribute__((ext_vector_type(4))) float f32x4;
typedef __attribute__((ext_vector_type(8))) short bf16x8;

static __device__ __forceinline__ unsigned short f2bf(float v) {
    union { __hip_bfloat16 h; unsigned short u; } cv;
    cv.h = __float2bfloat16(v);
    return cv.u;
}
static __device__ __forceinline__ float bf2f(unsigned short u) {
    union { unsigned short u; __hip_bfloat16 h; } cv;
    cv.u = u;
    return __bfloat162float(cv.h);
}

// ------------- prep A: [x^2, x] hi/lo -> [FAh(256) | FAl(256)] -------------
__global__ void prep_a_kernel(const float* __restrict__ x,
                              unsigned short* __restrict__ Ap) {
    int t = blockIdx.x * 256 + threadIdx.x;
    int row = t >> 7;
    int d   = t & 127;
    float v  = x[t];
    float x2 = v * v;
    unsigned short x2h = f2bf(x2);
    unsigned short x2l = f2bf(x2 - bf2f(x2h));
    unsigned short xh  = f2bf(v);
    unsigned short xl  = f2bf(v - bf2f(xh));
    unsigned short* a = Ap + (size_t)row * KPA;
    a[d]       = x2h;  a[128 + d] = xh;    // FAh
    a[256 + d] = x2l;  a[384 + d] = xl;    // FAl
}

// ------- prep B: single-bf16 [inv, -2*mean*inv] (256 wide) + c_i ---------
__global__ void prep_b_kernel(const float* __restrict__ mean,
                              const float* __restrict__ diag,
                              unsigned short* __restrict__ Bp,
                              float* __restrict__ cvec) {
    int wave = threadIdx.x >> 6, lane = threadIdx.x & 63;
    int row = blockIdx.x * 4 + wave;
    const float* mrow = mean + (size_t)row * DIM;
    const float* drow = diag + (size_t)row * DIM;
    unsigned short* b = Bp + (size_t)row * KPB;
    float csum = 0.0f;
#pragma unroll
    for (int j = 0; j < 2; ++j) {
        int d = lane + 64 * j;
        float m   = mrow[d];
        float dd  = fmaxf(drow[d], PD_THR);
        float inv = 1.0f / dd;
        float fm  = -2.0f * m * inv;
        csum += m * m * inv + logf(dd) + inv;
        b[d]       = f2bf(inv);
        b[128 + d] = f2bf(fm);
    }
#pragma unroll
    for (int off = 32; off > 0; off >>= 1) csum += __shfl_down(csum, off);
    if (lane == 0) cvec[row] = csum - (float)DIM;
}

// ---------- GEMM: 256x128 tile, 8 waves (4Mx2N), 3-deep counted-vmcnt ----------
// Per wave: 64x64 output = acc[4][4] of 16x16x32 frags. LDS 3 x 48 KB = 144 KB,
// 1 block/CU. Pipeline: prologue stages t=0,1,2; iter t waits vmcnt(12)
// (t done; t+1,t+2 in flight), computes, then stages t+3 into the buffer just
// freed -> each tile's loads have TWO full iterations to land.
// Slot-XOR LDS swizzle via pre-swizzled GLOBAL source (rule #21).
__global__ void __launch_bounds__(512, 2)
kl_gemm(const unsigned short* __restrict__ Ap,   // [BATCH][KPA]
        const unsigned short* __restrict__ Bp,   // [N_IN][KPB]
        const float* __restrict__ cvec,          // [N_IN]
        float* __restrict__ out) {               // [BATCH][N_IN]
    __shared__ __align__(16) unsigned short lds[3 * BUFE];  // 144 KiB

    // Per-XCD rectangular groups: grid 16 bx x 64 by = 1024 blocks.
    // xcd owns 4 bx x 32 by; fill bx-fastest -> ~32 co-resident blocks
    // cover a 4x8 window: A 1MB + B 0.5MB << 4MiB L2; per-XCD total 3MB.
    int bid0 = blockIdx.x;
    int xcd = bid0 & 7, g = bid0 >> 3;            // g in [0,128)
    int bx = (xcd & 3) * 4 + (g & 3);             // [0,16)
    int by = (xcd >> 2) * 32 + (g >> 2);          // [0,64)
    int m0 = bx * BM, n0 = by * BN;

    int tid  = threadIdx.x;
    int wave = tid >> 6, lane = tid & 63;
    int wr = wave >> 1, wc = wave & 1;            // 4M x 2N wave grid

    const int lrow  = lane >> 3;                  // row within 8-row chunk
    const int lslot = (lane & 7) ^ lrow;          // pre-swizzled 16B slot

    const unsigned short* gA = Ap + (size_t)(m0 + wave * 8 + lrow) * KPA + lslot * 8;
    const unsigned short* gB = Bp + (size_t)(n0 + wave * 16 + lrow) * KPB + lslot * 8;

    f32x4 acc[4][4];
#pragma unroll
    for (int m = 0; m < 4; ++m)
#pragma unroll
        for (int n = 0; n < 4; ++n) acc[m][n] = (f32x4){0.f, 0.f, 0.f, 0.f};

    // 6 global_load_lds per wave per K-tile (4 A-chunks + 2 B-chunks, 1KB each).
    auto STAGE = [&](int b, int t) {
        int k0a = t * BK;
        int k0b = (t & 3) * BK;                   // B stored once, wraps
        unsigned short* base = &lds[b * BUFE];
#pragma unroll
        for (int j = 0; j < 4; ++j)
            __builtin_amdgcn_global_load_lds(
                (const __attribute__((address_space(1))) void*)(gA + (size_t)j * 64 * KPA + k0a),
                (__attribute__((address_space(3))) void*)&base[(wave * 8 + j * 64) * 64],
                16, 0, 0);
#pragma unroll
        for (int j = 0; j < 2; ++j)
            __builtin_amdgcn_global_load_lds(
                (const __attribute__((address_space(1))) void*)(gB + (size_t)j * 8 * KPB + k0b),
                (__attribute__((address_space(3))) void*)&base[BM * BK + (wave * 16 + j * 8) * 64],
                16, 0, 0);
    };

    auto COMPUTE = [&](int b) {
        const unsigned short* La = &lds[b * BUFE];
        const unsigned short* Lb = &lds[b * BUFE + BM * BK];
#pragma unroll
        for (int kk = 0; kk < BK; kk += 32) {
            const int phys = (((kk >> 3) + (lane >> 4)) ^ (lane & 7)) * 8;
            bf16x8 af[4], bf[4];
#pragma unroll
            for (int m = 0; m < 4; ++m)
                af[m] = *(const bf16x8*)&La[(wr * 64 + m * 16 + (lane & 15)) * 64 + phys];
#pragma unroll
            for (int n = 0; n < 4; ++n)
                bf[n] = *(const bf16x8*)&Lb[(wc * 64 + n * 16 + (lane & 15)) * 64 + phys];
            __builtin_amdgcn_s_setprio(1);
#pragma unroll
            for (int m = 0; m < 4; ++m)
#pragma unroll
                for (int n = 0; n < 4; ++n)
                    acc[m][n] = __builtin_amdgcn_mfma_f32_16x16x32_bf16(
                        af[m], bf[n], acc[m][n], 0, 0, 0);
            __builtin_amdgcn_s_setprio(0);
        }
    };

    STAGE(0, 0);
    STAGE(1, 1);
    STAGE(2, 2);
    int b = 0;
#pragma unroll 1
    for (int t = 0; t < NT; ++t) {
        // Outstanding at entry: tiles t..min(t+2,NT-1), 6 loads each.
        if (t < NT - 2)      asm volatile("s_waitcnt vmcnt(12)" ::: "memory");
        else if (t == NT - 2) asm volatile("s_waitcnt vmcnt(6)"  ::: "memory");
        else                  asm volatile("s_waitcnt vmcnt(0)"  ::: "memory");
        __builtin_amdgcn_s_barrier();            // all waves' tile-t loads landed
        __builtin_amdgcn_sched_barrier(0);       // rule #18: pin ds_reads below
        COMPUTE(b);
        __builtin_amdgcn_s_barrier();            // all waves done reading buf b
        __builtin_amdgcn_sched_barrier(0);
        if (t + 3 < NT) STAGE(b, t + 3);         // refill the buffer just freed
        b = (b == 2) ? 0 : b + 1;
    }

    // ---- epilogue: per-wave LDS bounce -> float4 nt stores ----
    // acc[m][n][r] -> row m0+wr*64+m*16+(lane>>4)*4+r, col n0+wc*64+n*16+(lane&15)
    float* lbw = (float*)&lds[0] + wave * 1024;   // 4KB/wave, disjoint regions
    const int crow0 = m0 + wr * 64;
    const int ccol0 = n0 + wc * 64;
    const int lr = (lane >> 4) << 2;
    const int lc = lane & 15;
#pragma unroll
    for (int m = 0; m < 4; ++m) {
#pragma unroll
        for (int n = 0; n < 4; ++n)
#pragma unroll
            for (int r = 0; r < 4; ++r)
                lbw[(lr + r) * 64 + n * 16 + lc] = acc[m][n][r];
        // wave-private region: compiler lgkmcnt orders write->read
#pragma unroll
        for (int q = 0; q < 4; ++q) {
            int flat = q * 256 + lane * 4;
            int row  = flat >> 6;
            int col  = flat & 63;
            f32x4 v  = *(const f32x4*)&lbw[flat];
            f32x4 c4 = *(const f32x4*)&cvec[ccol0 + col];
            f32x4 o  = (v + c4) * 0.5f;
            __builtin_nontemporal_store(
                o, (f32x4*)&out[(size_t)(crow0 + m * 16 + row) * N_IN + ccol0 + col]);
        }
    }
}

extern "C" void kernel_launch(void* const* d_in, const int* in_sizes, int n_in_args,
                              void* d_out, int out_size, void* d_ws, size_t ws_size,
                              hipStream_t stream) {
    (void)in_sizes; (void)n_in_args; (void)out_size; (void)ws_size;
    const float* x    = (const float*)d_in[0];
    const float* mean = (const float*)d_in[1];
    const float* diag = (const float*)d_in[2];
    float* out = (float*)d_out;

    char* ws = (char*)d_ws;
    unsigned short* Bp = (unsigned short*)ws;                               // 4 MB
    unsigned short* Ap = (unsigned short*)(ws + (size_t)N_IN * KPB * 2);    // 4 MB
    float* cvec = (float*)(ws + (size_t)N_IN * KPB * 2 + (size_t)BATCH * KPA * 2);

    prep_a_kernel<<<BATCH * DIM / 256, 256, 0, stream>>>(x, Ap);
    prep_b_kernel<<<N_IN / 4, 256, 0, stream>>>(mean, diag, Bp, cvec);
    kl_gemm<<<(BATCH / BM) * (N_IN / BN), 512, 0, stream>>>(Ap, Bp, cvec, out);
}

// Round 9
// 187.299 us; speedup vs baseline: 1.0104x; 1.0104x over previous
//
#include <hip/hip_runtime.h>
#include <hip/hip_bf16.h>

// DiagonalEmbedder: out[b,i] = 0.5 * ( x2@inv.T - 2 x@(mean*inv).T + c_i )
// 2-term fp32-split bf16 GEMM (passed r7/r8): A' = [FAh|FAl] (4096x512),
// B = [inv,-2*mean*inv] (8192x256), logical K=512 (B wraps).
// r8 post-mortem: coarse 2-barrier loop caps staging at ~23 B/cy/CU no matter
// the buffer depth (r6 2-deep == r8 3-deep). This round: m196/m201's lever --
// FINE-GRAINED phases. Sub-tile = BK=32 slab (A16K+B16K), 4 rotating LDS slots
// (128KB), 16 phases: {vmcnt(8); barrier; issue-next-stage; 12 ds_read_b128;
// 32 MFMA setprio-wrapped; barrier}. Loads always 2 sub-tiles in flight.

#define BATCH 4096
#define N_IN  8192
#define DIM   128
#define KPA   512
#define KPB   256
#define PD_THR 1e-6f

#define BM 256
#define BN 256
#define NSUB 16             // sub-tiles of K=32 (A spans 512)
#define SLOT 16384          // shorts per slot: A 256x32 + B 256x32

typedef __attribute__((ext_vector_type(4))) float f32x4;
typedef __attribute__((ext_vector_type(8))) short bf16x8;

static __device__ __forceinline__ unsigned short f2bf(float v) {
    union { __hip_bfloat16 h; unsigned short u; } cv;
    cv.h = __float2bfloat16(v);
    return cv.u;
}
static __device__ __forceinline__ float bf2f(unsigned short u) {
    union { unsigned short u; __hip_bfloat16 h; } cv;
    cv.u = u;
    return __bfloat162float(cv.h);
}

// ------------- prep A: [x^2, x] hi/lo -> [FAh(256) | FAl(256)] -------------
__global__ void prep_a_kernel(const float* __restrict__ x,
                              unsigned short* __restrict__ Ap) {
    int t = blockIdx.x * 256 + threadIdx.x;
    int row = t >> 7;
    int d   = t & 127;
    float v  = x[t];
    float x2 = v * v;
    unsigned short x2h = f2bf(x2);
    unsigned short x2l = f2bf(x2 - bf2f(x2h));
    unsigned short xh  = f2bf(v);
    unsigned short xl  = f2bf(v - bf2f(xh));
    unsigned short* a = Ap + (size_t)row * KPA;
    a[d]       = x2h;  a[128 + d] = xh;    // FAh
    a[256 + d] = x2l;  a[384 + d] = xl;    // FAl
}

// ------- prep B: single-bf16 [inv, -2*mean*inv] (256 wide) + c_i ---------
__global__ void prep_b_kernel(const float* __restrict__ mean,
                              const float* __restrict__ diag,
                              unsigned short* __restrict__ Bp,
                              float* __restrict__ cvec) {
    int wave = threadIdx.x >> 6, lane = threadIdx.x & 63;
    int row = blockIdx.x * 4 + wave;
    const float* mrow = mean + (size_t)row * DIM;
    const float* drow = diag + (size_t)row * DIM;
    unsigned short* b = Bp + (size_t)row * KPB;
    float csum = 0.0f;
#pragma unroll
    for (int j = 0; j < 2; ++j) {
        int d = lane + 64 * j;
        float m   = mrow[d];
        float dd  = fmaxf(drow[d], PD_THR);
        float inv = 1.0f / dd;
        float fm  = -2.0f * m * inv;
        csum += m * m * inv + logf(dd) + inv;
        b[d]       = f2bf(inv);
        b[128 + d] = f2bf(fm);
    }
#pragma unroll
    for (int off = 32; off > 0; off >>= 1) csum += __shfl_down(csum, off);
    if (lane == 0) cvec[row] = csum - (float)DIM;
}

// -------- GEMM: 256x256 tile, 8 waves (2Mx4N), 16 fine phases, 4 LDS slots --------
// Per wave: 128x64 out = acc[8][4]. Slot s&3 holds sub-tile s: A[256 rows][32K]
// + B[256 cols][32K], each row/col 32 shorts = 4 x 16B slots.
// Swizzle: phys16Bslot = logical ^ ((row>>1)&3); stage realizes it by
// pre-swizzling the per-lane GLOBAL source (LDS dest linear, rule #21):
//   stage lane l -> row j*128+w*16+(l>>2), phys (l&3),
//   source k-slot (l&3)^((l>>3)&3)  [= phys ^ ((row>>1)&3), proven: (row>>1)&3
//   = (l>>3)&3 since j*128+w*16 contributes 0 mod 8 rows]
//   read lane -> row 16a+(lane&15): phys = (lane>>4) ^ ((lane>>1)&3).
// Content check: content(r,p) = k (p ^ ((r>>1)&3))*8; read wants (lane>>4)*8,
// fetches p = (lane>>4)^((r>>1)&3) -> content = (lane>>4)*8. QED.
// vmcnt ledger (4 loads/stage/wave): prologue stages s=0,1,2 (12 out).
// Phase s: wait vmcnt(8) [s's 4 land; s+1,s+2 stay in flight]; stage s+3
// issued AFTER the opening barrier (slot (s+3)&3 = (s-1)&3, all waves done
// with s-1 at that barrier). Tail: s=14 wait 4, s=15 wait 0.
__global__ void __launch_bounds__(512, 2)
kl_gemm(const unsigned short* __restrict__ Ap,   // [BATCH][KPA]
        const unsigned short* __restrict__ Bp,   // [N_IN][KPB]
        const float* __restrict__ cvec,          // [N_IN]
        float* __restrict__ out) {               // [BATCH][N_IN]
    __shared__ __align__(16) unsigned short lds[4 * SLOT];  // 128 KiB

    // Per-XCD rectangular groups: grid 16bx x 32by = 512 blocks; xcd owns
    // 4bx x 16by (A 1MB + B 2MB < 4MiB L2).
    int bid0 = blockIdx.x;
    int xcd = bid0 & 7, g = bid0 >> 3;            // g in [0,64)
    int bx = (xcd & 3) * 4 + (g & 3);             // [0,16)
    int by = (xcd >> 2) * 16 + (g >> 2);          // [0,32)
    int m0 = bx * BM, n0 = by * BN;

    int tid  = threadIdx.x;
    int wave = tid >> 6, lane = tid & 63;
    int wr = wave >> 2, wc = wave & 3;            // 2M x 4N wave grid

    // ---- staging source (pre-swizzled per-lane global addresses) ----
    const int srow  = lane >> 2;                  // 0..15
    const int sslot = (lane & 3) ^ ((lane >> 3) & 3);
    const unsigned short* gA = Ap + (size_t)(m0 + wave * 16 + srow) * KPA + sslot * 8;
    const unsigned short* gB = Bp + (size_t)(n0 + wave * 16 + srow) * KPB + sslot * 8;

    f32x4 acc[8][4];
#pragma unroll
    for (int m = 0; m < 8; ++m)
#pragma unroll
        for (int n = 0; n < 4; ++n) acc[m][n] = (f32x4){0.f, 0.f, 0.f, 0.f};

    // 4 global_load_lds per wave per sub-tile (2 A halves + 2 B halves, 1KB ea).
    auto STAGE = [&](int s) {
        unsigned short* base = &lds[(s & 3) * SLOT];
        int ka = s * 32;            // A k-offset (elements)
        int kb = (s & 7) * 32;      // B wraps (stored once, consumed twice)
#pragma unroll
        for (int j = 0; j < 2; ++j)
            __builtin_amdgcn_global_load_lds(
                (const __attribute__((address_space(1))) void*)(gA + (size_t)j * 128 * KPA + ka),
                (__attribute__((address_space(3))) void*)&base[(j * 128 + wave * 16) * 32],
                16, 0, 0);
#pragma unroll
        for (int j = 0; j < 2; ++j)
            __builtin_amdgcn_global_load_lds(
                (const __attribute__((address_space(1))) void*)(gB + (size_t)j * 128 * KPB + kb),
                (__attribute__((address_space(3))) void*)&base[8192 + (j * 128 + wave * 16) * 32],
                16, 0, 0);
    };

    STAGE(0); STAGE(1); STAGE(2);    // 12 loads outstanding per wave

    const int rphys = ((lane >> 4) ^ ((lane >> 1) & 3)) * 8;
    const int l15   = lane & 15;

#pragma unroll
    for (int s = 0; s < NSUB; ++s) {
        if (s <= 13)      asm volatile("s_waitcnt vmcnt(8)" ::: "memory");
        else if (s == 14) asm volatile("s_waitcnt vmcnt(4)" ::: "memory");
        else              asm volatile("s_waitcnt vmcnt(0)" ::: "memory");
        __builtin_amdgcn_s_barrier();            // sub-tile s visible to all
        __builtin_amdgcn_sched_barrier(0);
        if (s + 3 < NSUB) STAGE(s + 3);          // issue under the compute
        const unsigned short* La = &lds[(s & 3) * SLOT];
        const unsigned short* Lb = La + 8192;
        bf16x8 af[8], bf[4];
#pragma unroll
        for (int m = 0; m < 8; ++m)
            af[m] = *(const bf16x8*)&La[(wr * 128 + m * 16 + l15) * 32 + rphys];
#pragma unroll
        for (int n = 0; n < 4; ++n)
            bf[n] = *(const bf16x8*)&Lb[(wc * 64 + n * 16 + l15) * 32 + rphys];
        __builtin_amdgcn_s_setprio(1);
#pragma unroll
        for (int m = 0; m < 8; ++m)
#pragma unroll
            for (int n = 0; n < 4; ++n)
                acc[m][n] = __builtin_amdgcn_mfma_f32_16x16x32_bf16(
                    af[m], bf[n], acc[m][n], 0, 0, 0);
        __builtin_amdgcn_s_setprio(0);
        __builtin_amdgcn_s_barrier();            // all waves done with slot s
        __builtin_amdgcn_sched_barrier(0);
    }

    // ---- epilogue: per-wave LDS bounce -> float4 nt stores (r6-verified) ----
    // acc[m][n][r] -> row m0+wr*128+m*16+(lane>>4)*4+r, col n0+wc*64+n*16+(lane&15)
    float* lbw = (float*)&lds[0] + wave * 1024;   // 4KB/wave, disjoint regions
    const int crow0 = m0 + wr * 128;
    const int ccol0 = n0 + wc * 64;
    const int lr = (lane >> 4) << 2;
    const int lc = lane & 15;
#pragma unroll
    for (int m = 0; m < 8; ++m) {
#pragma unroll
        for (int n = 0; n < 4; ++n)
#pragma unroll
            for (int r = 0; r < 4; ++r)
                lbw[(lr + r) * 64 + n * 16 + lc] = acc[m][n][r];
        // wave-private region: compiler lgkmcnt orders write->read
#pragma unroll
        for (int q = 0; q < 4; ++q) {
            int flat = q * 256 + lane * 4;
            int row  = flat >> 6;
            int col  = flat & 63;
            f32x4 v  = *(const f32x4*)&lbw[flat];
            f32x4 c4 = *(const f32x4*)&cvec[ccol0 + col];
            f32x4 o  = (v + c4) * 0.5f;
            __builtin_nontemporal_store(
                o, (f32x4*)&out[(size_t)(crow0 + m * 16 + row) * N_IN + ccol0 + col]);
        }
    }
}

extern "C" void kernel_launch(void* const* d_in, const int* in_sizes, int n_in_args,
                              void* d_out, int out_size, void* d_ws, size_t ws_size,
                              hipStream_t stream) {
    (void)in_sizes; (void)n_in_args; (void)out_size; (void)ws_size;
    const float* x    = (const float*)d_in[0];
    const float* mean = (const float*)d_in[1];
    const float* diag = (const float*)d_in[2];
    float* out = (float*)d_out;

    char* ws = (char*)d_ws;
    unsigned short* Bp = (unsigned short*)ws;                               // 4 MB
    unsigned short* Ap = (unsigned short*)(ws + (size_t)N_IN * KPB * 2);    // 4 MB
    float* cvec = (float*)(ws + (size_t)N_IN * KPB * 2 + (size_t)BATCH * KPA * 2);

    prep_a_kernel<<<BATCH * DIM / 256, 256, 0, stream>>>(x, Ap);
    prep_b_kernel<<<N_IN / 4, 256, 0, stream>>>(mean, diag, Bp, cvec);
    kl_gemm<<<(BATCH / BM) * (N_IN / BN), 512, 0, stream>>>(Ap, Bp, cvec, out);
}